// Round 1
// baseline (9224.334 us; speedup 1.0000x reference)
//
#include <hip/hip_runtime.h>
#include <hip/hip_fp16.h>

// MINE estimator, dropout analytically marginalized:
//   mean(z1)  -> no-dropout forward (exact expectation; dropout unbiased there)
//   E[exp(z2)] = exp(b3) * prod_j (0.5 + 0.5*exp(2*a_j)),  a_j = w3_j*relu(h2_j)
//   permutation -> 20 fixed cyclic shifts (unbiased pairing estimator)
// b3 cancels between the two terms.

#define N_SAMP  131072
#define NMASK   (N_SAMP - 1)
#define HH      300
#define HPAD    320
#define CC      128
#define DD      256
#define KPASS   20
#define PSTRIDE 304

#define OFF_S    ((size_t)0)
#define OFF_W1P  ((size_t)1024)
#define OFF_W2P  (OFF_W1P + (size_t)HPAD*DD*4)
#define OFF_B1P  (OFF_W2P + (size_t)HPAD*HPAD*4)
#define OFF_B2P  (OFF_B1P + (size_t)HPAD*4)
#define OFF_W3P  (OFF_B2P + (size_t)HPAD*4)
#define OFF_P    (((OFF_W3P + (size_t)HPAD*4) + 4095) & ~(size_t)4095)
#define OFF_Q    (OFF_P + (size_t)N_SAMP*PSTRIDE*2)

__global__ void prep_kernel(const float* __restrict__ W1, const float* __restrict__ b1,
                            const float* __restrict__ W2, const float* __restrict__ b2,
                            const float* __restrict__ W3, char* __restrict__ ws)
{
    double* S   = (double*)(ws + OFF_S);
    float* w1p  = (float*)(ws + OFF_W1P);
    float* w2p  = (float*)(ws + OFF_W2P);
    float* b1p  = (float*)(ws + OFF_B1P);
    float* b2p  = (float*)(ws + OFF_B2P);
    float* w3p  = (float*)(ws + OFF_W3P);
    int tid = blockIdx.x * blockDim.x + threadIdx.x;
    int nth = gridDim.x * blockDim.x;
    if (tid <= KPASS) S[tid] = 0.0;
    for (int i = tid; i < HPAD * DD; i += nth) {
        int r = i >> 8, c = i & 255;
        w1p[i] = (r < HH) ? W1[r * DD + c] : 0.f;
    }
    for (int i = tid; i < HPAD * HPAD; i += nth) {
        int r = i / HPAD, c = i - r * HPAD;
        w2p[i] = (r < HH && c < HH) ? W2[r * HH + c] : 0.f;
    }
    for (int i = tid; i < HPAD; i += nth) {
        b1p[i] = (i < HH) ? b1[i] : 0.f;
        b2p[i] = (i < HH) ? b2[i] : 0.f;
        w3p[i] = (i < HH) ? W3[i] : 0.f;
    }
}

// P = relu-less U*W1a^T + b1 ; Q = V*W1b^T   (stored fp16, row stride PSTRIDE)
__global__ __launch_bounds__(256, 2)
void fc1_kernel(const float* __restrict__ x, const int* __restrict__ ind,
                char* __restrict__ ws)
{
    const float* w1p = (const float*)(ws + OFF_W1P);
    const float* b1p = (const float*)(ws + OFF_B1P);
    const int sel    = blockIdx.y;          // 0 -> P (u, +b1), 1 -> Q (v)
    __half* out      = (__half*)(ws + (sel == 0 ? OFF_P : OFF_Q));
    const int colOff = sel * CC;
    const int i0     = blockIdx.x * 64;

    __shared__ __align__(16) float At[CC][64];   // [k][m] transposed x tile, 32 KB
    __shared__ __align__(16) float Bt[64][64];   // swizzled W1 tile, 16 KB

    const int t  = threadIdx.x;
    const int tx = t & 15, ty = t >> 4;

    { // stage transposed gathered x
        const int m = t >> 2;
        const int r = ind[i0 + m];
        const float* xr = x + (size_t)r * DD + colOff;
        const int cb = (t & 3) * 4;
        #pragma unroll
        for (int it = 0; it < 8; ++it) {
            const int c = cb + it * 16;
            const float4 v = *(const float4*)(xr + c);
            At[c + 0][m] = v.x; At[c + 1][m] = v.y;
            At[c + 2][m] = v.z; At[c + 3][m] = v.w;
        }
    }

    for (int jc = 0; jc < HPAD; jc += 64) {
        float acc[4][4] = {};
        for (int kc = 0; kc < 2; ++kc) {
            const int k0 = kc * 64;
            __syncthreads();
            { // stage Bt (xor-swizzled 4-float chunks)
                const int kk4 = tx * 4;
                #pragma unroll
                for (int s = 0; s < 4; ++s) {
                    const int jl = ty + s * 16;
                    const float4 v = *(const float4*)(w1p + (size_t)(jc + jl) * DD + colOff + k0 + kk4);
                    const float vv[4] = {v.x, v.y, v.z, v.w};
                    #pragma unroll
                    for (int q = 0; q < 4; ++q) {
                        const int kk = kk4 + q;
                        Bt[kk][(((jl >> 2) ^ (kk >> 2)) & 15) * 4 + (jl & 3)] = vv[q];
                    }
                }
            }
            __syncthreads();
            #pragma unroll 4
            for (int kk = 0; kk < 64; ++kk) {
                const float4 bv = *(const float4*)&Bt[kk][((tx ^ (kk >> 2)) & 15) * 4];
                const float4 av = *(const float4*)&At[k0 + kk][ty * 4];
                acc[0][0] = fmaf(av.x, bv.x, acc[0][0]); acc[0][1] = fmaf(av.x, bv.y, acc[0][1]);
                acc[0][2] = fmaf(av.x, bv.z, acc[0][2]); acc[0][3] = fmaf(av.x, bv.w, acc[0][3]);
                acc[1][0] = fmaf(av.y, bv.x, acc[1][0]); acc[1][1] = fmaf(av.y, bv.y, acc[1][1]);
                acc[1][2] = fmaf(av.y, bv.z, acc[1][2]); acc[1][3] = fmaf(av.y, bv.w, acc[1][3]);
                acc[2][0] = fmaf(av.z, bv.x, acc[2][0]); acc[2][1] = fmaf(av.z, bv.y, acc[2][1]);
                acc[2][2] = fmaf(av.z, bv.z, acc[2][2]); acc[2][3] = fmaf(av.z, bv.w, acc[2][3]);
                acc[3][0] = fmaf(av.w, bv.x, acc[3][0]); acc[3][1] = fmaf(av.w, bv.y, acc[3][1]);
                acc[3][2] = fmaf(av.w, bv.z, acc[3][2]); acc[3][3] = fmaf(av.w, bv.w, acc[3][3]);
            }
        }
        const int jbase = jc + tx * 4;
        if (jbase < PSTRIDE) {
            float bb[4] = {0.f, 0.f, 0.f, 0.f};
            if (sel == 0) {
                const float4 b4 = *(const float4*)(b1p + jbase);
                bb[0] = b4.x; bb[1] = b4.y; bb[2] = b4.z; bb[3] = b4.w;
            }
            #pragma unroll
            for (int mm = 0; mm < 4; ++mm) {
                const int m = ty * 4 + mm;
                float v0 = acc[mm][0] + bb[0];
                float v1 = acc[mm][1] + bb[1];
                float v2 = acc[mm][2] + bb[2];
                float v3 = acc[mm][3] + bb[3];
                if (jbase + 0 >= HH) v0 = 0.f;
                if (jbase + 1 >= HH) v1 = 0.f;
                if (jbase + 2 >= HH) v2 = 0.f;
                if (jbase + 3 >= HH) v3 = 0.f;
                __half2 h01 = __floats2half2_rn(v0, v1);
                __half2 h23 = __floats2half2_rn(v2, v3);
                uint2 st;
                st.x = *(const unsigned*)&h01;
                st.y = *(const unsigned*)&h23;
                *(uint2*)(out + (size_t)(i0 + m) * PSTRIDE + jbase) = st;
            }
        }
    }
}

// Per pass p: h1 = relu(P_i + Q_{(i+shift) mod n}); h2 = h1*W2^T + b2; a = w3*relu(h2)
// p==0: accumulate sum_i sum_j a_ij       -> S[0]
// p>0 : accumulate sum_i exp(sum_j [softplus(2a)-ln2])  -> S[p]
__global__ __launch_bounds__(256, 2)
void fc23_kernel(char* __restrict__ ws)
{
    const float* w2p = (const float*)(ws + OFF_W2P);
    const float* b2p = (const float*)(ws + OFF_B2P);
    const float* w3p = (const float*)(ws + OFF_W3P);
    const __half* P  = (const __half*)(ws + OFF_P);
    const __half* Q  = (const __half*)(ws + OFF_Q);
    double* S        = (double*)(ws + OFF_S);

    const int p  = blockIdx.y;
    const int i0 = blockIdx.x * 64;
    const unsigned shift = (p == 0) ? 0u : (((unsigned)p * 2654435761u) & NMASK);

    __shared__ __align__(16) __half At[HPAD][64];   // [k][m] h1 tile fp16, 40 KB
    __shared__ __align__(16) float  Bt[64][64];     // swizzled W2 tile, 16 KB
    __shared__ float red[16];

    const int t  = threadIdx.x;
    const int tx = t & 15, ty = t >> 4;

    { // stage h1 = relu(P+Q), transposed into At; zero pad rows
        const int m = t >> 2;
        const __half* pr = P + (size_t)(i0 + m) * PSTRIDE;
        const __half* qr = Q + (size_t)(((unsigned)(i0 + m) + shift) & NMASK) * PSTRIDE;
        for (int c8 = (t & 3); c8 < 38; c8 += 4) {
            const int c = c8 * 8;
            const uint4 pv = *(const uint4*)(pr + c);
            const uint4 qv = *(const uint4*)(qr + c);
            const unsigned pw[4] = {pv.x, pv.y, pv.z, pv.w};
            const unsigned qw[4] = {qv.x, qv.y, qv.z, qv.w};
            #pragma unroll
            for (int q = 0; q < 4; ++q) {
                const float2 pf = __half22float2(*(const __half2*)&pw[q]);
                const float2 qf = __half22float2(*(const __half2*)&qw[q]);
                const int k = c + q * 2;
                float h0 = fmaxf(pf.x + qf.x, 0.f);
                float h1 = fmaxf(pf.y + qf.y, 0.f);
                At[k    ][m] = __float2half((k     < HH) ? h0 : 0.f);
                At[k + 1][m] = __float2half((k + 1 < HH) ? h1 : 0.f);
            }
        }
        // zero rows 304..319
        *(uint2*)&At[PSTRIDE + (t >> 4)][(t & 15) * 4] = make_uint2(0u, 0u);
    }

    float pse[4] = {0.f, 0.f, 0.f, 0.f};
    const float LN2 = 0.69314718055994531f;

    for (int jc = 0; jc < HPAD; jc += 64) {
        float acc[4][4] = {};
        for (int kc = 0; kc < 5; ++kc) {
            const int k0 = kc * 64;
            __syncthreads();
            { // stage Bt
                const int kk4 = tx * 4;
                #pragma unroll
                for (int s = 0; s < 4; ++s) {
                    const int jl = ty + s * 16;
                    const float4 v = *(const float4*)(w2p + (size_t)(jc + jl) * HPAD + k0 + kk4);
                    const float vv[4] = {v.x, v.y, v.z, v.w};
                    #pragma unroll
                    for (int q = 0; q < 4; ++q) {
                        const int kk = kk4 + q;
                        Bt[kk][(((jl >> 2) ^ (kk >> 2)) & 15) * 4 + (jl & 3)] = vv[q];
                    }
                }
            }
            __syncthreads();
            #pragma unroll 4
            for (int kk = 0; kk < 64; ++kk) {
                const float4 bv = *(const float4*)&Bt[kk][((tx ^ (kk >> 2)) & 15) * 4];
                const uint2 au = *(const uint2*)&At[k0 + kk][ty * 4];
                const float2 f01 = __half22float2(*(const __half2*)&au.x);
                const float2 f23 = __half22float2(*(const __half2*)&au.y);
                const float a0 = f01.x, a1 = f01.y, a2 = f23.x, a3 = f23.y;
                acc[0][0] = fmaf(a0, bv.x, acc[0][0]); acc[0][1] = fmaf(a0, bv.y, acc[0][1]);
                acc[0][2] = fmaf(a0, bv.z, acc[0][2]); acc[0][3] = fmaf(a0, bv.w, acc[0][3]);
                acc[1][0] = fmaf(a1, bv.x, acc[1][0]); acc[1][1] = fmaf(a1, bv.y, acc[1][1]);
                acc[1][2] = fmaf(a1, bv.z, acc[1][2]); acc[1][3] = fmaf(a1, bv.w, acc[1][3]);
                acc[2][0] = fmaf(a2, bv.x, acc[2][0]); acc[2][1] = fmaf(a2, bv.y, acc[2][1]);
                acc[2][2] = fmaf(a2, bv.z, acc[2][2]); acc[2][3] = fmaf(a2, bv.w, acc[2][3]);
                acc[3][0] = fmaf(a3, bv.x, acc[3][0]); acc[3][1] = fmaf(a3, bv.y, acc[3][1]);
                acc[3][2] = fmaf(a3, bv.z, acc[3][2]); acc[3][3] = fmaf(a3, bv.w, acc[3][3]);
            }
        }
        // epilogue: padded j>=300 contribute exactly 0 (w2p rows and b2p/w3p are 0)
        const int jbase = jc + tx * 4;
        const float4 b2v = *(const float4*)(b2p + jbase);
        const float4 w3v = *(const float4*)(w3p + jbase);
        const float bb[4] = {b2v.x, b2v.y, b2v.z, b2v.w};
        const float w3[4] = {w3v.x, w3v.y, w3v.z, w3v.w};
        #pragma unroll
        for (int mm = 0; mm < 4; ++mm) {
            #pragma unroll
            for (int jj = 0; jj < 4; ++jj) {
                const float h2 = acc[mm][jj] + bb[jj];
                const float a  = w3[jj] * fmaxf(h2, 0.f);
                if (p == 0) {
                    pse[mm] += a;
                } else {
                    const float e = __expf(2.f * a);
                    pse[mm] += __logf(0.5f + 0.5f * e);   // softplus(2a) - ln2
                }
            }
        }
        (void)LN2;
    }

    // reduce across the 16 tx lanes (consecutive lanes within a wave)
    #pragma unroll
    for (int mm = 0; mm < 4; ++mm) {
        float v = pse[mm];
        v += __shfl_xor(v, 1);
        v += __shfl_xor(v, 2);
        v += __shfl_xor(v, 4);
        v += __shfl_xor(v, 8);
        pse[mm] = v;
    }
    float mine = 0.f;
    if (tx == 0) {
        #pragma unroll
        for (int mm = 0; mm < 4; ++mm)
            mine += (p == 0) ? pse[mm] : __expf(pse[mm]);
    }
    __syncthreads();
    if (tx == 0) red[ty] = mine;
    __syncthreads();
    if (t == 0) {
        float tot = 0.f;
        #pragma unroll
        for (int i = 0; i < 16; ++i) tot += red[i];
        atomicAdd(&S[p], (double)tot);
    }
}

__global__ void fin_kernel(char* __restrict__ ws, float* __restrict__ out)
{
    if (threadIdx.x == 0 && blockIdx.x == 0) {
        const double* S = (const double*)(ws + OFF_S);
        double m1 = S[0] / (double)N_SAMP;
        double a = 0.0;
        for (int p = 1; p <= KPASS; ++p) a += log(S[p] / (double)N_SAMP);
        out[0] = (float)(m1 - a / (double)KPASS);
    }
}

extern "C" void kernel_launch(void* const* d_in, const int* in_sizes, int n_in,
                              void* d_out, int out_size, void* d_ws, size_t ws_size,
                              hipStream_t stream)
{
    const float* x  = (const float*)d_in[0];
    const int* ind  = (const int*)d_in[1];
    const float* W1 = (const float*)d_in[2];
    const float* b1 = (const float*)d_in[3];
    const float* W2 = (const float*)d_in[4];
    const float* b2 = (const float*)d_in[5];
    const float* W3 = (const float*)d_in[6];
    char* ws = (char*)d_ws;

    hipLaunchKernelGGL(prep_kernel, dim3(512), dim3(256), 0, stream, W1, b1, W2, b2, W3, ws);
    hipLaunchKernelGGL(fc1_kernel, dim3(N_SAMP / 64, 2), dim3(256), 0, stream, x, ind, ws);
    hipLaunchKernelGGL(fc23_kernel, dim3(N_SAMP / 64, KPASS + 1), dim3(256), 0, stream, ws);
    hipLaunchKernelGGL(fin_kernel, dim3(1), dim3(64), 0, stream, ws, (float*)d_out);
}

// Round 2
// 1801.593 us; speedup vs baseline: 5.1201x; 5.1201x over previous
//
#include <hip/hip_runtime.h>
#include <hip/hip_fp16.h>

// MINE estimator, dropout analytically marginalized:
//   mean(z1)  -> no-dropout forward (exact expectation; dropout unbiased there)
//   E[exp(z2)] = exp(b3) * prod_j (0.5 + 0.5*exp(2*a_j)),  a_j = w3_j*relu(h2_j)
//   permutation -> 20 fixed cyclic shifts (unbiased pairing estimator)
// b3 cancels between the two terms.
// R2: fc23 rewritten on MFMA f16 (16x16x32), h1 staged in A-fragment LDS layout.

#define N_SAMP  131072
#define NMASK   (N_SAMP - 1)
#define HH      300
#define HPAD    320
#define CC      128
#define DD      256
#define KPASS   20
#define PSTRIDE 320

#define OFF_S    ((size_t)0)
#define OFF_W1P  ((size_t)1024)
#define OFF_B1P  (OFF_W1P + (size_t)HPAD*DD*4)
#define OFF_B2P  (OFF_B1P + (size_t)HPAD*4)
#define OFF_W3P  (OFF_B2P + (size_t)HPAD*4)
#define OFF_W2H  (OFF_W3P + (size_t)HPAD*4)
#define OFF_P    (((OFF_W2H + (size_t)HPAD*HPAD*2) + 4095) & ~(size_t)4095)
#define OFF_Q    (OFF_P + (size_t)N_SAMP*PSTRIDE*2)

typedef _Float16 f16x8 __attribute__((ext_vector_type(8)));
typedef float    fx4   __attribute__((ext_vector_type(4)));

__global__ void prep_kernel(const float* __restrict__ W1, const float* __restrict__ b1,
                            const float* __restrict__ W2, const float* __restrict__ b2,
                            const float* __restrict__ W3, char* __restrict__ ws)
{
    double* S      = (double*)(ws + OFF_S);
    float* w1p     = (float*)(ws + OFF_W1P);
    _Float16* w2h  = (_Float16*)(ws + OFF_W2H);
    float* b1p     = (float*)(ws + OFF_B1P);
    float* b2p     = (float*)(ws + OFF_B2P);
    float* w3p     = (float*)(ws + OFF_W3P);
    int tid = blockIdx.x * blockDim.x + threadIdx.x;
    int nth = gridDim.x * blockDim.x;
    if (tid <= KPASS) S[tid] = 0.0;
    for (int i = tid; i < HPAD * DD; i += nth) {
        int r = i >> 8, c = i & 255;
        w1p[i] = (r < HH) ? W1[r * DD + c] : 0.f;
    }
    for (int i = tid; i < HPAD * HPAD; i += nth) {
        int r = i / HPAD, c = i - r * HPAD;
        w2h[i] = (r < HH && c < HH) ? (_Float16)W2[r * HH + c] : (_Float16)0.f;
    }
    for (int i = tid; i < HPAD; i += nth) {
        b1p[i] = (i < HH) ? b1[i] : 0.f;
        b2p[i] = (i < HH) ? b2[i] : 0.f;
        w3p[i] = (i < HH) ? W3[i] : 0.f;
    }
}

// P = relu-less U*W1a^T + b1 ; Q = V*W1b^T   (stored fp16, row stride PSTRIDE=320, j>=300 zeroed)
__global__ __launch_bounds__(256, 2)
void fc1_kernel(const float* __restrict__ x, const int* __restrict__ ind,
                char* __restrict__ ws)
{
    const float* w1p = (const float*)(ws + OFF_W1P);
    const float* b1p = (const float*)(ws + OFF_B1P);
    const int sel    = blockIdx.y;          // 0 -> P (u, +b1), 1 -> Q (v)
    __half* out      = (__half*)(ws + (sel == 0 ? OFF_P : OFF_Q));
    const int colOff = sel * CC;
    const int i0     = blockIdx.x * 64;

    __shared__ __align__(16) float At[CC][64];
    __shared__ __align__(16) float Bt[64][64];

    const int t  = threadIdx.x;
    const int tx = t & 15, ty = t >> 4;

    { // stage transposed gathered x
        const int m = t >> 2;
        const int r = ind[i0 + m];
        const float* xr = x + (size_t)r * DD + colOff;
        const int cb = (t & 3) * 4;
        #pragma unroll
        for (int it = 0; it < 8; ++it) {
            const int c = cb + it * 16;
            const float4 v = *(const float4*)(xr + c);
            At[c + 0][m] = v.x; At[c + 1][m] = v.y;
            At[c + 2][m] = v.z; At[c + 3][m] = v.w;
        }
    }

    for (int jc = 0; jc < HPAD; jc += 64) {
        float acc[4][4] = {};
        for (int kc = 0; kc < 2; ++kc) {
            const int k0 = kc * 64;
            __syncthreads();
            {
                const int kk4 = tx * 4;
                #pragma unroll
                for (int s = 0; s < 4; ++s) {
                    const int jl = ty + s * 16;
                    const float4 v = *(const float4*)(w1p + (size_t)(jc + jl) * DD + colOff + k0 + kk4);
                    const float vv[4] = {v.x, v.y, v.z, v.w};
                    #pragma unroll
                    for (int q = 0; q < 4; ++q) {
                        const int kk = kk4 + q;
                        Bt[kk][(((jl >> 2) ^ (kk >> 2)) & 15) * 4 + (jl & 3)] = vv[q];
                    }
                }
            }
            __syncthreads();
            #pragma unroll 4
            for (int kk = 0; kk < 64; ++kk) {
                const float4 bv = *(const float4*)&Bt[kk][((tx ^ (kk >> 2)) & 15) * 4];
                const float4 av = *(const float4*)&At[k0 + kk][ty * 4];
                acc[0][0] = fmaf(av.x, bv.x, acc[0][0]); acc[0][1] = fmaf(av.x, bv.y, acc[0][1]);
                acc[0][2] = fmaf(av.x, bv.z, acc[0][2]); acc[0][3] = fmaf(av.x, bv.w, acc[0][3]);
                acc[1][0] = fmaf(av.y, bv.x, acc[1][0]); acc[1][1] = fmaf(av.y, bv.y, acc[1][1]);
                acc[1][2] = fmaf(av.y, bv.z, acc[1][2]); acc[1][3] = fmaf(av.y, bv.w, acc[1][3]);
                acc[2][0] = fmaf(av.z, bv.x, acc[2][0]); acc[2][1] = fmaf(av.z, bv.y, acc[2][1]);
                acc[2][2] = fmaf(av.z, bv.z, acc[2][2]); acc[2][3] = fmaf(av.z, bv.w, acc[2][3]);
                acc[3][0] = fmaf(av.w, bv.x, acc[3][0]); acc[3][1] = fmaf(av.w, bv.y, acc[3][1]);
                acc[3][2] = fmaf(av.w, bv.z, acc[3][2]); acc[3][3] = fmaf(av.w, bv.w, acc[3][3]);
            }
        }
        const int jbase = jc + tx * 4;
        {
            float bb[4] = {0.f, 0.f, 0.f, 0.f};
            if (sel == 0) {
                const float4 b4 = *(const float4*)(b1p + jbase);
                bb[0] = b4.x; bb[1] = b4.y; bb[2] = b4.z; bb[3] = b4.w;
            }
            #pragma unroll
            for (int mm = 0; mm < 4; ++mm) {
                const int m = ty * 4 + mm;
                float v0 = acc[mm][0] + bb[0];
                float v1 = acc[mm][1] + bb[1];
                float v2 = acc[mm][2] + bb[2];
                float v3 = acc[mm][3] + bb[3];
                if (jbase + 0 >= HH) v0 = 0.f;
                if (jbase + 1 >= HH) v1 = 0.f;
                if (jbase + 2 >= HH) v2 = 0.f;
                if (jbase + 3 >= HH) v3 = 0.f;
                __half2 h01 = __floats2half2_rn(v0, v1);
                __half2 h23 = __floats2half2_rn(v2, v3);
                uint2 st;
                st.x = *(const unsigned*)&h01;
                st.y = *(const unsigned*)&h23;
                *(uint2*)(out + (size_t)(i0 + m) * PSTRIDE + jbase) = st;
            }
        }
    }
}

// MFMA fc2+fc3: h1 = relu(P_i + Q_{(i+shift)&mask}) fp16; h2 = h1*W2h^T; analytic epilogue.
// Block: 128 rows, 4 waves, wave w owns cols [80w, 80w+80) as 5 16-col MFMA tiles.
__global__ __launch_bounds__(256, 2)
void fc23_kernel(char* __restrict__ ws)
{
    const _Float16* w2h = (const _Float16*)(ws + OFF_W2H);
    const float* b2p = (const float*)(ws + OFF_B2P);
    const float* w3p = (const float*)(ws + OFF_W3P);
    const _Float16* P = (const _Float16*)(ws + OFF_P);
    const _Float16* Q = (const _Float16*)(ws + OFF_Q);
    double* S = (double*)(ws + OFF_S);

    const int p  = blockIdx.y;
    const int i0 = blockIdx.x * 128;
    const unsigned shift = (p == 0) ? 0u : (((unsigned)p * 2654435761u) & NMASK);

    __shared__ __align__(16) char lds[81920];   // h1 A-fragments (80 KB), reused for reductions
    _Float16* At = (_Float16*)lds;

    const int t    = threadIdx.x;
    const int lane = t & 63, w = t >> 6;
    const int tx   = lane & 15, quad = lane >> 4;

    { // stage h1 = relu(P+Q) directly into MFMA A-fragment layout
        const int m = t >> 1, c = t & 1;
        const int mt = m >> 4, ml = m & 15;
        const _Float16* pr = P + (size_t)(i0 + m) * PSTRIDE;
        const _Float16* qr = Q + (size_t)(((unsigned)(i0 + m) + shift) & NMASK) * PSTRIDE;
        #pragma unroll 4
        for (int i = 0; i < 20; ++i) {
            const int ch = c + 2 * i;            // 8-half chunk index, k0 = ch*8
            const int kt = ch >> 2, qd = ch & 3;
            f16x8 hp = *(const f16x8*)(pr + ch * 8);
            f16x8 hq = *(const f16x8*)(qr + ch * 8);
            f16x8 s  = hp + hq;
            s = __builtin_elementwise_max(s, (f16x8)(_Float16)0);
            *(f16x8*)(At + ((size_t)(mt * 10 + kt) * 64 + qd * 16 + ml) * 8) = s;
        }
    }
    __syncthreads();

    fx4 acc[8][5] = {};
    const int colw = w * 80;

    for (int kt = 0; kt < 10; ++kt) {
        f16x8 bf[5];
        #pragma unroll
        for (int n = 0; n < 5; ++n)
            bf[n] = *(const f16x8*)(w2h + (size_t)(colw + n * 16 + tx) * HPAD + kt * 32 + quad * 8);
        #pragma unroll
        for (int mh = 0; mh < 2; ++mh) {
            f16x8 af[4];
            #pragma unroll
            for (int mi = 0; mi < 4; ++mi)
                af[mi] = *(const f16x8*)(At + ((size_t)((mh * 4 + mi) * 10 + kt) * 64 + lane) * 8);
            #pragma unroll
            for (int mi = 0; mi < 4; ++mi)
                #pragma unroll
                for (int n = 0; n < 5; ++n)
                    acc[mh * 4 + mi][n] =
                        __builtin_amdgcn_mfma_f32_16x16x32_f16(af[mi], bf[n], acc[mh * 4 + mi][n], 0, 0, 0);
        }
    }
    __syncthreads();   // all waves done reading At; LDS now reusable

    // epilogue: C layout col=lane&15(tx), row=quad*4+reg within each 16x16 tile
    float b2v[5], w3v[5];
    #pragma unroll
    for (int n = 0; n < 5; ++n) {
        b2v[n] = b2p[colw + n * 16 + tx];
        w3v[n] = w3p[colw + n * 16 + tx];
    }
    float* part = (float*)lds;                  // [128 rows][4 waves]
    #pragma unroll
    for (int mt = 0; mt < 8; ++mt) {
        float ps[4] = {0.f, 0.f, 0.f, 0.f};
        #pragma unroll
        for (int n = 0; n < 5; ++n)
            #pragma unroll
            for (int r = 0; r < 4; ++r) {
                const float h2 = acc[mt][n][r] + b2v[n];
                const float a  = w3v[n] * fmaxf(h2, 0.f);
                if (p == 0) ps[r] += a;
                else        ps[r] += __logf(fmaf(0.5f, __expf(2.f * a), 0.5f)); // softplus(2a)-ln2
            }
        #pragma unroll
        for (int r = 0; r < 4; ++r) {
            float v = ps[r];
            v += __shfl_xor(v, 1); v += __shfl_xor(v, 2);
            v += __shfl_xor(v, 4); v += __shfl_xor(v, 8);
            ps[r] = v;
        }
        if (tx == 0) {
            #pragma unroll
            for (int r = 0; r < 4; ++r)
                part[(mt * 16 + quad * 4 + r) * 4 + w] = ps[r];
        }
    }
    __syncthreads();

    float tot = 0.f;
    if (t < 128) {
        const float s = part[t * 4 + 0] + part[t * 4 + 1] + part[t * 4 + 2] + part[t * 4 + 3];
        tot = (p == 0) ? s : __expf(s);
    }
    tot += __shfl_xor(tot, 1);  tot += __shfl_xor(tot, 2);
    tot += __shfl_xor(tot, 4);  tot += __shfl_xor(tot, 8);
    tot += __shfl_xor(tot, 16); tot += __shfl_xor(tot, 32);
    float* red = (float*)(lds + 4096);
    if (lane == 0) red[w] = tot;
    __syncthreads();
    if (t == 0) atomicAdd(&S[p], (double)(red[0] + red[1] + red[2] + red[3]));
}

__global__ void fin_kernel(char* __restrict__ ws, float* __restrict__ out)
{
    if (threadIdx.x == 0 && blockIdx.x == 0) {
        const double* S = (const double*)(ws + OFF_S);
        double m1 = S[0] / (double)N_SAMP;
        double a = 0.0;
        for (int p = 1; p <= KPASS; ++p) a += log(S[p] / (double)N_SAMP);
        out[0] = (float)(m1 - a / (double)KPASS);
    }
}

extern "C" void kernel_launch(void* const* d_in, const int* in_sizes, int n_in,
                              void* d_out, int out_size, void* d_ws, size_t ws_size,
                              hipStream_t stream)
{
    const float* x  = (const float*)d_in[0];
    const int* ind  = (const int*)d_in[1];
    const float* W1 = (const float*)d_in[2];
    const float* b1 = (const float*)d_in[3];
    const float* W2 = (const float*)d_in[4];
    const float* b2 = (const float*)d_in[5];
    const float* W3 = (const float*)d_in[6];
    char* ws = (char*)d_ws;

    hipLaunchKernelGGL(prep_kernel, dim3(512), dim3(256), 0, stream, W1, b1, W2, b2, W3, ws);
    hipLaunchKernelGGL(fc1_kernel, dim3(N_SAMP / 64, 2), dim3(256), 0, stream, x, ind, ws);
    hipLaunchKernelGGL(fc23_kernel, dim3(N_SAMP / 128, KPASS + 1), dim3(256), 0, stream, ws);
    hipLaunchKernelGGL(fin_kernel, dim3(1), dim3(64), 0, stream, ws, (float*)d_out);
}

// Round 3
// 1582.716 us; speedup vs baseline: 5.8282x; 1.1383x over previous
//
#include <hip/hip_runtime.h>
#include <hip/hip_fp16.h>

// MINE estimator, dropout analytically marginalized:
//   mean(z1)  -> no-dropout forward (exact expectation)
//   E[exp(z2)] = exp(b3) * prod_j (0.5 + 0.5*exp(2*a_j)),  a_j = w3_j*relu(h2_j)
//   permutation -> 20 fixed cyclic shifts (unbiased pairing estimator)
// R3: B-fragment-major weight layouts (coalesced frag loads), bank-conflict-free
//     A staging (slot = ml*4+qd), register double-buffered B, fc1 on MFMA.

#define N_SAMP  131072
#define NMASK   (N_SAMP - 1)
#define HH      300
#define HPAD    320
#define DD      256
#define KPASS   20
#define PSTRIDE 320

#define OFF_S    ((size_t)0)
#define OFF_B1P  ((size_t)1024)
#define OFF_B2P  ((size_t)2304)
#define OFF_W3P  ((size_t)3584)
#define OFF_W1B  ((size_t)8192)                       // [20 nt][8 kt][64 lane][8] f16
#define OFF_W2B  (OFF_W1B + (size_t)163840)           // [20 nt][10 kt][64 lane][8] f16
#define OFF_P    (OFF_W2B + (size_t)204800)           // = 376832, 4096-aligned
#define OFF_Q    (OFF_P + (size_t)N_SAMP*PSTRIDE*2)

typedef _Float16 f16x8 __attribute__((ext_vector_type(8)));
typedef float    fx4   __attribute__((ext_vector_type(4)));

__global__ void prep_kernel(const float* __restrict__ W1, const float* __restrict__ b1,
                            const float* __restrict__ W2, const float* __restrict__ b2,
                            const float* __restrict__ W3, char* __restrict__ ws)
{
    double* S     = (double*)(ws + OFF_S);
    float* b1p    = (float*)(ws + OFF_B1P);
    float* b2p    = (float*)(ws + OFF_B2P);
    float* w3p    = (float*)(ws + OFF_W3P);
    _Float16* w1b = (_Float16*)(ws + OFF_W1B);
    _Float16* w2b = (_Float16*)(ws + OFF_W2B);
    int tid = blockIdx.x * blockDim.x + threadIdx.x;
    int nth = gridDim.x * blockDim.x;
    if (tid <= KPASS) S[tid] = 0.0;
    for (int i = tid; i < HPAD; i += nth) {
        b1p[i] = (i < HH) ? b1[i] : 0.f;
        b2p[i] = (i < HH) ? b2[i] : 0.f;
        w3p[i] = (i < HH) ? W3[i] : 0.f;
    }
    // w1b: frag (nt,kt): value = W1[n][k], n = nt*16+tx, k = kt*32+quad*8+j (K=256)
    for (int i = tid; i < 20 * 8 * 64 * 8; i += nth) {
        const int j = i & 7, lane = (i >> 3) & 63, rem = i >> 9;
        const int kt = rem & 7, nt = rem >> 3;
        const int n = nt * 16 + (lane & 15);
        const int k = kt * 32 + (lane >> 4) * 8 + j;
        w1b[i] = (n < HH) ? (_Float16)W1[n * DD + k] : (_Float16)0.f;
    }
    // w2b: frag (nt,kt): value = W2[n][k], k = kt*32+quad*8+j (K=320 padded)
    for (int i = tid; i < 20 * 10 * 64 * 8; i += nth) {
        const int j = i & 7, lane = (i >> 3) & 63, rem = i >> 9;
        const int kt = rem % 10, nt = rem / 10;
        const int n = nt * 16 + (lane & 15);
        const int k = kt * 32 + (lane >> 4) * 8 + j;
        w2b[i] = (n < HH && k < HH) ? (_Float16)W2[n * HH + k] : (_Float16)0.f;
    }
}

// fc1 on MFMA: gather x rows -> fp16 A-frags in LDS; P = u*W1a^T + b1 (kt 0..3),
// Q = v*W1b^T (kt 4..7). Epilogue transposes through LDS for coalesced stores.
__global__ __launch_bounds__(256, 2)
void fc1_kernel(const float* __restrict__ x, const int* __restrict__ ind,
                char* __restrict__ ws)
{
    const _Float16* w1b = (const _Float16*)(ws + OFF_W1B);
    const float* b1p    = (const float*)(ws + OFF_B1P);
    const int i0 = blockIdx.x * 128;

    __shared__ __align__(16) char lds[65536];   // At [8 kt][8 mt][64 slot][8] f16
    _Float16* At  = (_Float16*)lds;
    _Float16* buf = (_Float16*)lds;             // transpose buf, overlaps kt 0..3 after P

    const int t    = threadIdx.x;
    const int lane = t & 63, w = t >> 6;
    const int tx   = lane & 15, quad = lane >> 4;
    const int colw = w * 80;

    { // stage gathered x -> fp16 A-frag layout (2 threads/row, 64 B contiguous per pair)
        const int m = t >> 1, c = t & 1;
        const int mt = m >> 4, ml = m & 15;
        const int r = ind[i0 + m];
        const float* xr = x + (size_t)r * DD;
        #pragma unroll
        for (int i = 0; i < 16; ++i) {
            const int ch = 2 * i + c;           // 8-float chunk, k = ch*8..ch*8+7
            const int kt = ch >> 2, qd = ch & 3;
            const float4 f0 = *(const float4*)(xr + ch * 8);
            const float4 f1 = *(const float4*)(xr + ch * 8 + 4);
            f16x8 h;
            h[0] = (_Float16)f0.x; h[1] = (_Float16)f0.y;
            h[2] = (_Float16)f0.z; h[3] = (_Float16)f0.w;
            h[4] = (_Float16)f1.x; h[5] = (_Float16)f1.y;
            h[6] = (_Float16)f1.z; h[7] = (_Float16)f1.w;
            *(f16x8*)(At + ((size_t)(kt * 8 + mt) * 64 + ml * 4 + qd) * 8) = h;
        }
    }
    __syncthreads();

    #pragma unroll
    for (int ph = 0; ph < 2; ++ph) {
        fx4 acc[8][5] = {};
        #pragma unroll
        for (int kt = 0; kt < 4; ++kt) {
            const int ktg = ph * 4 + kt;
            f16x8 bf[5];
            #pragma unroll
            for (int n = 0; n < 5; ++n)
                bf[n] = *(const f16x8*)(w1b + ((size_t)((w * 5 + n) * 8 + ktg) * 64 + lane) * 8);
            #pragma unroll
            for (int mh = 0; mh < 2; ++mh) {
                f16x8 af[4];
                #pragma unroll
                for (int mi = 0; mi < 4; ++mi)
                    af[mi] = *(const f16x8*)(At + ((size_t)(ktg * 8 + mh * 4 + mi) * 64 + tx * 4 + quad) * 8);
                #pragma unroll
                for (int mi = 0; mi < 4; ++mi)
                    #pragma unroll
                    for (int n = 0; n < 5; ++n)
                        acc[mh * 4 + mi][n] =
                            __builtin_amdgcn_mfma_f32_16x16x32_f16(af[mi], bf[n], acc[mh * 4 + mi][n], 0, 0, 0);
            }
        }
        _Float16* out = (_Float16*)(ws + (ph ? OFF_Q : OFF_P));
        #pragma unroll
        for (int g = 0; g < 4; ++g) {
            __syncthreads();   // waves done with kt 0..3 reads (P) / prior buf use
            #pragma unroll
            for (int mi = 0; mi < 2; ++mi) {
                const int mt = g * 2 + mi;
                #pragma unroll
                for (int n = 0; n < 5; ++n) {
                    const int col = colw + n * 16 + tx;   // b1p/w1b padding makes col>=300 -> 0
                    const float bb = (ph == 0) ? b1p[col] : 0.f;
                    #pragma unroll
                    for (int r = 0; r < 4; ++r) {
                        const int row32 = mi * 16 + quad * 4 + r;
                        buf[row32 * 328 + col] = (_Float16)(acc[mt][n][r] + bb);
                    }
                }
            }
            __syncthreads();
            #pragma unroll
            for (int s5 = 0; s5 < 5; ++s5) {
                const int idx = t + s5 * 256;
                const int rr = idx / 40, cc = idx - rr * 40;
                *(uint4*)(out + (size_t)(i0 + g * 32 + rr) * PSTRIDE + cc * 8) =
                    *(const uint4*)(buf + rr * 328 + cc * 8);
            }
        }
        __syncthreads();
    }
}

// fc2+fc3: h1 = relu(P_i + Q_{(i+shift)&mask}); h2 = h1*W2^T + b2; analytic epilogue.
// 128 rows/block, 4 waves col-split (80 cols each); B-frags coalesced from w2b.
__global__ __launch_bounds__(256, 2)
void fc23_kernel(char* __restrict__ ws)
{
    const _Float16* w2b = (const _Float16*)(ws + OFF_W2B);
    const float* b2p = (const float*)(ws + OFF_B2P);
    const float* w3p = (const float*)(ws + OFF_W3P);
    const _Float16* P = (const _Float16*)(ws + OFF_P);
    const _Float16* Q = (const _Float16*)(ws + OFF_Q);
    double* S = (double*)(ws + OFF_S);

    const int p  = blockIdx.y;
    const int i0 = blockIdx.x * 128;
    const unsigned shift = (p == 0) ? 0u : (((unsigned)p * 2654435761u) & NMASK);

    __shared__ __align__(16) char lds[81920];   // At [8 mt][10 kt][64 slot][8] f16
    _Float16* At = (_Float16*)lds;

    const int t    = threadIdx.x;
    const int lane = t & 63, w = t >> 6;
    const int tx   = lane & 15, quad = lane >> 4;
    const int colw = w * 80;

    { // stage h1 = relu(P+Q): 4 threads/row, full-line reads, conflict-free writes
        const int c = t & 3, m0 = t >> 2;
        #pragma unroll
        for (int s = 0; s < 2; ++s) {
            const int m = m0 + s * 64;
            const int mt = m >> 4, ml = m & 15;
            const _Float16* pr = P + (size_t)(i0 + m) * PSTRIDE;
            const _Float16* qr = Q + (size_t)(((unsigned)(i0 + m) + shift) & NMASK) * PSTRIDE;
            #pragma unroll
            for (int i = 0; i < 10; ++i) {
                const int ch = c + i * 4;       // kt = i, qd = c
                f16x8 hp = *(const f16x8*)(pr + ch * 8);
                f16x8 hq = *(const f16x8*)(qr + ch * 8);
                f16x8 sv = hp + hq;
                sv = __builtin_elementwise_max(sv, (f16x8)(_Float16)0);
                *(f16x8*)(At + ((size_t)(mt * 10 + i) * 64 + ml * 4 + c) * 8) = sv;
            }
        }
    }
    __syncthreads();

    fx4 acc[8][5] = {};
    const _Float16* wb = w2b + (size_t)(w * 5) * 10 * 512 + (size_t)lane * 8;
    f16x8 bA[5], bB[5];
    #pragma unroll
    for (int n = 0; n < 5; ++n) bA[n] = *(const f16x8*)(wb + (size_t)(n * 10) * 512);

    #pragma unroll
    for (int kt = 0; kt < 10; ++kt) {
        f16x8* bc = (kt & 1) ? bB : bA;
        f16x8* bn = (kt & 1) ? bA : bB;
        if (kt < 9) {
            #pragma unroll
            for (int n = 0; n < 5; ++n)
                bn[n] = *(const f16x8*)(wb + (size_t)(n * 10 + kt + 1) * 512);
        }
        #pragma unroll
        for (int mh = 0; mh < 2; ++mh) {
            f16x8 af[4];
            #pragma unroll
            for (int mi = 0; mi < 4; ++mi)
                af[mi] = *(const f16x8*)(At + ((size_t)((mh * 4 + mi) * 10 + kt) * 64 + tx * 4 + quad) * 8);
            #pragma unroll
            for (int mi = 0; mi < 4; ++mi)
                #pragma unroll
                for (int n = 0; n < 5; ++n)
                    acc[mh * 4 + mi][n] =
                        __builtin_amdgcn_mfma_f32_16x16x32_f16(af[mi], bc[n], acc[mh * 4 + mi][n], 0, 0, 0);
        }
    }
    __syncthreads();   // At no longer needed; reuse LDS for reductions

    float b2v[5], w3v[5];
    #pragma unroll
    for (int n = 0; n < 5; ++n) {
        b2v[n] = b2p[colw + n * 16 + tx];
        w3v[n] = w3p[colw + n * 16 + tx];
    }
    float* part = (float*)lds;                  // [128 rows][4 waves]
    #pragma unroll
    for (int mt = 0; mt < 8; ++mt) {
        float ps[4] = {0.f, 0.f, 0.f, 0.f};
        #pragma unroll
        for (int n = 0; n < 5; ++n)
            #pragma unroll
            for (int r = 0; r < 4; ++r) {
                const float h2 = acc[mt][n][r] + b2v[n];
                const float a  = w3v[n] * fmaxf(h2, 0.f);
                if (p == 0) ps[r] += a;
                else        ps[r] += __logf(fmaf(0.5f, __expf(2.f * a), 0.5f)); // softplus(2a)-ln2
            }
        #pragma unroll
        for (int r = 0; r < 4; ++r) {
            float v = ps[r];
            v += __shfl_xor(v, 1); v += __shfl_xor(v, 2);
            v += __shfl_xor(v, 4); v += __shfl_xor(v, 8);
            ps[r] = v;
        }
        if (tx == 0) {
            #pragma unroll
            for (int r = 0; r < 4; ++r)
                part[(mt * 16 + quad * 4 + r) * 4 + w] = ps[r];
        }
    }
    __syncthreads();

    float tot = 0.f;
    if (t < 128) {
        const float s = part[t * 4 + 0] + part[t * 4 + 1] + part[t * 4 + 2] + part[t * 4 + 3];
        tot = (p == 0) ? s : __expf(s);
    }
    tot += __shfl_xor(tot, 1);  tot += __shfl_xor(tot, 2);
    tot += __shfl_xor(tot, 4);  tot += __shfl_xor(tot, 8);
    tot += __shfl_xor(tot, 16); tot += __shfl_xor(tot, 32);
    float* red = (float*)(lds + 4096);
    if (lane == 0) red[w] = tot;
    __syncthreads();
    if (t == 0) atomicAdd(&S[p], (double)(red[0] + red[1] + red[2] + red[3]));
}

__global__ void fin_kernel(char* __restrict__ ws, float* __restrict__ out)
{
    if (threadIdx.x == 0 && blockIdx.x == 0) {
        const double* S = (const double*)(ws + OFF_S);
        double m1 = S[0] / (double)N_SAMP;
        double a = 0.0;
        for (int p = 1; p <= KPASS; ++p) a += log(S[p] / (double)N_SAMP);
        out[0] = (float)(m1 - a / (double)KPASS);
    }
}

extern "C" void kernel_launch(void* const* d_in, const int* in_sizes, int n_in,
                              void* d_out, int out_size, void* d_ws, size_t ws_size,
                              hipStream_t stream)
{
    const float* x  = (const float*)d_in[0];
    const int* ind  = (const int*)d_in[1];
    const float* W1 = (const float*)d_in[2];
    const float* b1 = (const float*)d_in[3];
    const float* W2 = (const float*)d_in[4];
    const float* b2 = (const float*)d_in[5];
    const float* W3 = (const float*)d_in[6];
    char* ws = (char*)d_ws;

    hipLaunchKernelGGL(prep_kernel, dim3(512), dim3(256), 0, stream, W1, b1, W2, b2, W3, ws);
    hipLaunchKernelGGL(fc1_kernel, dim3(N_SAMP / 128), dim3(256), 0, stream, x, ind, ws);
    hipLaunchKernelGGL(fc23_kernel, dim3(N_SAMP / 128, KPASS + 1), dim3(256), 0, stream, ws);
    hipLaunchKernelGGL(fin_kernel, dim3(1), dim3(64), 0, stream, ws, (float*)d_out);
}

// Round 5
// 1422.177 us; speedup vs baseline: 6.4861x; 1.1129x over previous
//
#include <hip/hip_runtime.h>
#include <hip/hip_fp16.h>

// MINE estimator, dropout analytically marginalized:
//   mean(z1)  -> no-dropout forward (exact expectation)
//   E[exp(z2)] = exp(b3) * prod_j (0.5 + 0.5*exp(2*a_j)),  a_j = w3_j*relu(h2_j)
//   permutation -> 20 fixed cyclic shifts (unbiased pairing estimator)
// R4b: fc23 M-tile 64 (40 KB LDS -> 4 blocks/CU), b2 folded into K=320 padding
//     (h1 col 300 = 1, W2 row 300 = b2), epilogue in exp2/log2 domain with
//     per-n-tile products (1 log per 20 elements instead of 1 per element).
//     Fix: __builtin_amdgcn_logf (v_log_f32 == log2) instead of nonexistent log2f.

#define N_SAMP  131072
#define NMASK   (N_SAMP - 1)
#define HH      300
#define HPAD    320
#define DD      256
#define KPASS   20
#define PSTRIDE 320

#define OFF_S    ((size_t)0)
#define OFF_B1P  ((size_t)1024)
#define OFF_B2P  ((size_t)2304)
#define OFF_W3P  ((size_t)3584)
#define OFF_C2   ((size_t)4864)
#define OFF_W1B  ((size_t)8192)                       // [20 nt][8 kt][64 lane][8] f16
#define OFF_W2B  (OFF_W1B + (size_t)163840)           // [20 nt][10 kt][64 lane][8] f16
#define OFF_P    (OFF_W2B + (size_t)204800)
#define OFF_Q    (OFF_P + (size_t)N_SAMP*PSTRIDE*2)

typedef _Float16 f16x8 __attribute__((ext_vector_type(8)));
typedef float    fx4   __attribute__((ext_vector_type(4)));

__global__ void prep_kernel(const float* __restrict__ W1, const float* __restrict__ b1,
                            const float* __restrict__ W2, const float* __restrict__ b2,
                            const float* __restrict__ W3, char* __restrict__ ws)
{
    double* S     = (double*)(ws + OFF_S);
    float* b1p    = (float*)(ws + OFF_B1P);
    float* b2p    = (float*)(ws + OFF_B2P);
    float* w3p    = (float*)(ws + OFF_W3P);
    float* c2p    = (float*)(ws + OFF_C2);
    _Float16* w1b = (_Float16*)(ws + OFF_W1B);
    _Float16* w2b = (_Float16*)(ws + OFF_W2B);
    int tid = blockIdx.x * blockDim.x + threadIdx.x;
    int nth = gridDim.x * blockDim.x;
    if (tid <= KPASS) S[tid] = 0.0;
    for (int i = tid; i < HPAD; i += nth) {
        b1p[i] = (i < HH) ? b1[i] : 0.f;
        b2p[i] = (i < HH) ? b2[i] : 0.f;
        w3p[i] = (i < HH) ? W3[i] : 0.f;
        c2p[i] = (i < HH) ? 2.8853900817779268f * W3[i] : 0.f;  // 2*log2(e)*w3
    }
    // w1b: frag (nt,kt): value = W1[n][k], n = nt*16+tx, k = kt*32+quad*8+j (K=256)
    for (int i = tid; i < 20 * 8 * 64 * 8; i += nth) {
        const int j = i & 7, lane = (i >> 3) & 63, rem = i >> 9;
        const int kt = rem & 7, nt = rem >> 3;
        const int n = nt * 16 + (lane & 15);
        const int k = kt * 32 + (lane >> 4) * 8 + j;
        w1b[i] = (n < HH) ? (_Float16)W1[n * DD + k] : (_Float16)0.f;
    }
    // w2b: frag (nt,kt): value = W2[n][k]; row k==300 carries b2 (bias fold)
    for (int i = tid; i < 20 * 10 * 64 * 8; i += nth) {
        const int j = i & 7, lane = (i >> 3) & 63, rem = i >> 9;
        const int kt = rem % 10, nt = rem / 10;
        const int n = nt * 16 + (lane & 15);
        const int k = kt * 32 + (lane >> 4) * 8 + j;
        float v = 0.f;
        if (n < HH) {
            if (k < HH)       v = W2[n * HH + k];
            else if (k == HH) v = b2[n];
        }
        w2b[i] = (_Float16)v;
    }
}

// fc1 on MFMA: gather x rows -> fp16 A-frags in LDS; P = u*W1a^T + b1 (kt 0..3),
// Q = v*W1b^T (kt 4..7). Epilogue transposes through LDS for coalesced stores.
__global__ __launch_bounds__(256, 2)
void fc1_kernel(const float* __restrict__ x, const int* __restrict__ ind,
                char* __restrict__ ws)
{
    const _Float16* w1b = (const _Float16*)(ws + OFF_W1B);
    const float* b1p    = (const float*)(ws + OFF_B1P);
    const int i0 = blockIdx.x * 128;

    __shared__ __align__(16) char lds[65536];   // At [8 kt][8 mt][64 slot][8] f16
    _Float16* At  = (_Float16*)lds;
    _Float16* buf = (_Float16*)lds;

    const int t    = threadIdx.x;
    const int lane = t & 63, w = t >> 6;
    const int tx   = lane & 15, quad = lane >> 4;
    const int colw = w * 80;

    {
        const int m = t >> 1, c = t & 1;
        const int mt = m >> 4, ml = m & 15;
        const int r = ind[i0 + m];
        const float* xr = x + (size_t)r * DD;
        #pragma unroll
        for (int i = 0; i < 16; ++i) {
            const int ch = 2 * i + c;
            const int kt = ch >> 2, qd = ch & 3;
            const float4 f0 = *(const float4*)(xr + ch * 8);
            const float4 f1 = *(const float4*)(xr + ch * 8 + 4);
            f16x8 h;
            h[0] = (_Float16)f0.x; h[1] = (_Float16)f0.y;
            h[2] = (_Float16)f0.z; h[3] = (_Float16)f0.w;
            h[4] = (_Float16)f1.x; h[5] = (_Float16)f1.y;
            h[6] = (_Float16)f1.z; h[7] = (_Float16)f1.w;
            *(f16x8*)(At + ((size_t)(kt * 8 + mt) * 64 + ml * 4 + qd) * 8) = h;
        }
    }
    __syncthreads();

    #pragma unroll
    for (int ph = 0; ph < 2; ++ph) {
        fx4 acc[8][5] = {};
        #pragma unroll
        for (int kt = 0; kt < 4; ++kt) {
            const int ktg = ph * 4 + kt;
            f16x8 bf[5];
            #pragma unroll
            for (int n = 0; n < 5; ++n)
                bf[n] = *(const f16x8*)(w1b + ((size_t)((w * 5 + n) * 8 + ktg) * 64 + lane) * 8);
            #pragma unroll
            for (int mh = 0; mh < 2; ++mh) {
                f16x8 af[4];
                #pragma unroll
                for (int mi = 0; mi < 4; ++mi)
                    af[mi] = *(const f16x8*)(At + ((size_t)(ktg * 8 + mh * 4 + mi) * 64 + tx * 4 + quad) * 8);
                #pragma unroll
                for (int mi = 0; mi < 4; ++mi)
                    #pragma unroll
                    for (int n = 0; n < 5; ++n)
                        acc[mh * 4 + mi][n] =
                            __builtin_amdgcn_mfma_f32_16x16x32_f16(af[mi], bf[n], acc[mh * 4 + mi][n], 0, 0, 0);
            }
        }
        _Float16* out = (_Float16*)(ws + (ph ? OFF_Q : OFF_P));
        #pragma unroll
        for (int g = 0; g < 4; ++g) {
            __syncthreads();
            #pragma unroll
            for (int mi = 0; mi < 2; ++mi) {
                const int mt = g * 2 + mi;
                #pragma unroll
                for (int n = 0; n < 5; ++n) {
                    const int col = colw + n * 16 + tx;
                    const float bb = (ph == 0) ? b1p[col] : 0.f;
                    #pragma unroll
                    for (int r = 0; r < 4; ++r) {
                        const int row32 = mi * 16 + quad * 4 + r;
                        buf[row32 * 328 + col] = (_Float16)(acc[mt][n][r] + bb);
                    }
                }
            }
            __syncthreads();
            #pragma unroll
            for (int s5 = 0; s5 < 5; ++s5) {
                const int idx = t + s5 * 256;
                const int rr = idx / 40, cc = idx - rr * 40;
                *(uint4*)(out + (size_t)(i0 + g * 32 + rr) * PSTRIDE + cc * 8) =
                    *(const uint4*)(buf + rr * 328 + cc * 8);
            }
        }
        __syncthreads();
    }
}

// fc2+fc3: h1 = relu(P_i + Q_{(i+shift)&mask}) [col 300 = 1 -> b2 fold];
// h2 = h1*W2b^T; epilogue in exp2/log2 domain. M=64, 4 waves N-split, 40 KB LDS.
__global__ __launch_bounds__(256, 4)
void fc23_kernel(char* __restrict__ ws)
{
    const _Float16* w2b = (const _Float16*)(ws + OFF_W2B);
    const float* w3p = (const float*)(ws + OFF_W3P);
    const float* c2p = (const float*)(ws + OFF_C2);
    const _Float16* P = (const _Float16*)(ws + OFF_P);
    const _Float16* Q = (const _Float16*)(ws + OFF_Q);
    double* S = (double*)(ws + OFF_S);

    const int p  = blockIdx.y;
    const int i0 = blockIdx.x * 64;
    const unsigned shift = (p == 0) ? 0u : (((unsigned)p * 2654435761u) & NMASK);

    __shared__ __align__(16) char lds[40960];   // At [4 mt][10 kt][64 slot][8] f16
    _Float16* At = (_Float16*)lds;

    const int t    = threadIdx.x;
    const int lane = t & 63, w = t >> 6;
    const int tx   = lane & 15, quad = lane >> 4;
    const int colw = w * 80;

    // prefetch first B-frags before the staging barrier
    const _Float16* wb = w2b + (size_t)(w * 5) * 10 * 512 + (size_t)lane * 8;
    f16x8 bA[5], bB[5];
    #pragma unroll
    for (int n = 0; n < 5; ++n) bA[n] = *(const f16x8*)(wb + (size_t)(n * 10) * 512);

    { // stage h1 = relu(P+Q): 4 threads/row; chunk ch = c + 4i; col 300 -> 1.0
        const int c = t & 3, m = t >> 2;
        const int mt = m >> 4, ml = m & 15;
        const _Float16* pr = P + (size_t)(i0 + m) * PSTRIDE;
        const _Float16* qr = Q + (size_t)(((unsigned)(i0 + m) + shift) & NMASK) * PSTRIDE;
        #pragma unroll
        for (int i = 0; i < 10; ++i) {
            const int ch = c + i * 4;
            f16x8 hp = *(const f16x8*)(pr + ch * 8);
            f16x8 hq = *(const f16x8*)(qr + ch * 8);
            f16x8 sv = hp + hq;
            sv = __builtin_elementwise_max(sv, (f16x8)(_Float16)0);
            if (ch == 37) sv[4] = (_Float16)1.f;   // k=300: bias column
            *(f16x8*)(At + ((size_t)(mt * 10 + i) * 64 + ml * 4 + c) * 8) = sv;
        }
    }
    __syncthreads();

    fx4 acc[4][5] = {};
    #pragma unroll
    for (int kt = 0; kt < 10; ++kt) {
        f16x8* bc = (kt & 1) ? bB : bA;
        f16x8* bn = (kt & 1) ? bA : bB;
        if (kt < 9) {
            #pragma unroll
            for (int n = 0; n < 5; ++n)
                bn[n] = *(const f16x8*)(wb + (size_t)(n * 10 + kt + 1) * 512);
        }
        f16x8 af[4];
        #pragma unroll
        for (int mi = 0; mi < 4; ++mi)
            af[mi] = *(const f16x8*)(At + ((size_t)(mi * 10 + kt) * 64 + tx * 4 + quad) * 8);
        #pragma unroll
        for (int mi = 0; mi < 4; ++mi)
            #pragma unroll
            for (int n = 0; n < 5; ++n)
                acc[mi][n] =
                    __builtin_amdgcn_mfma_f32_16x16x32_f16(af[mi], bc[n], acc[mi][n], 0, 0, 0);
    }
    __syncthreads();   // At no longer needed; reuse LDS

    float w3v[5], c2v[5];
    #pragma unroll
    for (int n = 0; n < 5; ++n) {
        w3v[n] = w3p[colw + n * 16 + tx];
        c2v[n] = c2p[colw + n * 16 + tx];
    }
    float* part = (float*)lds;                  // [64 rows][4 waves]
    #pragma unroll
    for (int mt = 0; mt < 4; ++mt) {
        float ps[4];
        if (p == 0) {
            ps[0] = ps[1] = ps[2] = ps[3] = 0.f;
            #pragma unroll
            for (int n = 0; n < 5; ++n)
                #pragma unroll
                for (int r = 0; r < 4; ++r)
                    ps[r] = fmaf(w3v[n], fmaxf(acc[mt][n][r], 0.f), ps[r]);
        } else {
            float pr[4] = {1.f, 1.f, 1.f, 1.f};
            #pragma unroll
            for (int n = 0; n < 5; ++n)
                #pragma unroll
                for (int r = 0; r < 4; ++r) {
                    const float hr = fmaxf(acc[mt][n][r], 0.f);
                    const float u  = __builtin_amdgcn_exp2f(c2v[n] * hr);  // e^{2a}
                    pr[r] *= fmaf(0.5f, u, 0.5f);
                }
            #pragma unroll
            for (int r = 0; r < 4; ++r)
                ps[r] = __builtin_amdgcn_logf(pr[r]);   // v_log_f32 = log2
        }
        #pragma unroll
        for (int r = 0; r < 4; ++r) {
            float v = ps[r];
            v += __shfl_xor(v, 1); v += __shfl_xor(v, 2);
            v += __shfl_xor(v, 4); v += __shfl_xor(v, 8);
            ps[r] = v;
        }
        if (tx == 0) {
            #pragma unroll
            for (int r = 0; r < 4; ++r)
                part[(mt * 16 + quad * 4 + r) * 4 + w] = ps[r];
        }
    }
    __syncthreads();

    float tot = 0.f;
    if (t < 64) {
        const float s = part[t * 4 + 0] + part[t * 4 + 1] + part[t * 4 + 2] + part[t * 4 + 3];
        tot = (p == 0) ? s : __builtin_amdgcn_exp2f(s);
    }
    tot += __shfl_xor(tot, 1);  tot += __shfl_xor(tot, 2);
    tot += __shfl_xor(tot, 4);  tot += __shfl_xor(tot, 8);
    tot += __shfl_xor(tot, 16); tot += __shfl_xor(tot, 32);
    if (t == 0) atomicAdd(&S[p], (double)tot);
}

__global__ void fin_kernel(char* __restrict__ ws, float* __restrict__ out)
{
    if (threadIdx.x == 0 && blockIdx.x == 0) {
        const double* S = (const double*)(ws + OFF_S);
        double m1 = S[0] / (double)N_SAMP;
        double a = 0.0;
        for (int p = 1; p <= KPASS; ++p) a += log(S[p] / (double)N_SAMP);
        out[0] = (float)(m1 - a / (double)KPASS);
    }
}

extern "C" void kernel_launch(void* const* d_in, const int* in_sizes, int n_in,
                              void* d_out, int out_size, void* d_ws, size_t ws_size,
                              hipStream_t stream)
{
    const float* x  = (const float*)d_in[0];
    const int* ind  = (const int*)d_in[1];
    const float* W1 = (const float*)d_in[2];
    const float* b1 = (const float*)d_in[3];
    const float* W2 = (const float*)d_in[4];
    const float* b2 = (const float*)d_in[5];
    const float* W3 = (const float*)d_in[6];
    char* ws = (char*)d_ws;

    hipLaunchKernelGGL(prep_kernel, dim3(512), dim3(256), 0, stream, W1, b1, W2, b2, W3, ws);
    hipLaunchKernelGGL(fc1_kernel, dim3(N_SAMP / 128), dim3(256), 0, stream, x, ind, ws);
    hipLaunchKernelGGL(fc23_kernel, dim3(N_SAMP / 64, KPASS + 1), dim3(256), 0, stream, ws);
    hipLaunchKernelGGL(fin_kernel, dim3(1), dim3(64), 0, stream, ws, (float*)d_out);
}